// Round 6
// baseline (91.827 us; speedup 1.0000x reference)
//
#include <hip/hip_runtime.h>

#define D_MODEL   2048
#define F4T       (D_MODEL / 4)        // 512 float4 per token
#define THREADS   256
#define NSTRIP    8                    // D_MODEL / (64 lanes * 4 floats)

typedef float f4 __attribute__((ext_vector_type(4)));

// Fused: one wave per 2 tokens. x read from HBM exactly once (held in VGPRs),
// W_to/W_from read once per wave (shared by both tokens), out written NT.
__global__ __launch_bounds__(THREADS, 4)
void hypercube_fused_kernel(const float* __restrict__ x,
                            const float* __restrict__ W_to,
                            const float* __restrict__ W_from,
                            const float* __restrict__ log_temp,
                            const float* __restrict__ scale_p,
                            float* __restrict__ out,
                            int n_tokens)
{
    const int tid   = threadIdx.x;
    const int lane  = tid & 63;
    const int wave  = tid >> 6;
    const int tok0  = (blockIdx.x * 4 + wave) * 2;
    if (tok0 >= n_tokens) return;

    const f4* __restrict__ X4  = reinterpret_cast<const f4*>(x);
    const f4* __restrict__ WT4 = reinterpret_cast<const f4*>(W_to);
    const f4* __restrict__ WF4 = reinterpret_cast<const f4*>(W_from);
    f4* __restrict__ O4 = reinterpret_cast<f4*>(out);

    const size_t xb0 = (size_t)tok0 * F4T;
    const size_t xb1 = xb0 + F4T;

    // ---- issue ALL x loads first (32 independent dwordx4, fills mem pipe) --
    f4 xa[NSTRIP], xbv[NSTRIP];
#pragma unroll
    for (int s = 0; s < NSTRIP; ++s)
        xa[s] = X4[xb0 + s * 64 + lane];
#pragma unroll
    for (int s = 0; s < NSTRIP; ++s)
        xbv[s] = X4[xb1 + s * 64 + lane];

    // ---- projection: z[t][k] = sum_d x[d]*W_to[k][d]; W_to from L2 ----
    float z0[4] = {0.f,0.f,0.f,0.f};
    float z1[4] = {0.f,0.f,0.f,0.f};
#pragma unroll
    for (int s = 0; s < NSTRIP; ++s) {
        const int fi = s * 64 + lane;
        const f4 w0 = WT4[0*512 + fi];
        const f4 w1 = WT4[1*512 + fi];
        const f4 w2 = WT4[2*512 + fi];
        const f4 w3 = WT4[3*512 + fi];
        const f4 a = xa[s];
        const f4 b = xbv[s];
        z0[0] += a.x*w0.x + a.y*w0.y + a.z*w0.z + a.w*w0.w;
        z0[1] += a.x*w1.x + a.y*w1.y + a.z*w1.z + a.w*w1.w;
        z0[2] += a.x*w2.x + a.y*w2.y + a.z*w2.z + a.w*w2.w;
        z0[3] += a.x*w3.x + a.y*w3.y + a.z*w3.z + a.w*w3.w;
        z1[0] += b.x*w0.x + b.y*w0.y + b.z*w0.z + b.w*w0.w;
        z1[1] += b.x*w1.x + b.y*w1.y + b.z*w1.z + b.w*w1.w;
        z1[2] += b.x*w2.x + b.y*w2.y + b.z*w2.z + b.w*w2.w;
        z1[3] += b.x*w3.x + b.y*w3.y + b.z*w3.z + b.w*w3.w;
    }

    // ---- wave64 butterfly reduce (8 sums) — no LDS, no barrier ----
#pragma unroll
    for (int off = 32; off >= 1; off >>= 1) {
#pragma unroll
        for (int k = 0; k < 4; ++k) {
            z0[k] += __shfl_xor(z0[k], off);
            z1[k] += __shfl_xor(z1[k], off);
        }
    }

    // ---- scalars ----
    float temp = __expf(log_temp[0]);
    temp = fminf(fmaxf(temp, 0.01f), 5.0f);
    const float inv_temp = 1.0f / temp;
    const float scale = scale_p[0];

    // ---- softmax over 16 hypercube vertices (fast hw transcendentals) ----
    float q[2][4];
#pragma unroll
    for (int t = 0; t < 2; ++t) {
        const float* zz = (t == 0) ? z0 : z1;
        float logits[16];
        float m = -1e30f;
#pragma unroll
        for (int k = 0; k < 16; ++k) {
            float ssum = 0.f;
#pragma unroll
            for (int j = 0; j < 4; ++j) {
                const float dz = zz[j] - (float)((k >> j) & 1);
                ssum += dz * dz;
            }
            logits[k] = -__builtin_amdgcn_sqrtf(ssum) * inv_temp;
            m = fmaxf(m, logits[k]);
        }
        float esum = 0.f;
        float qq[4] = {0.f,0.f,0.f,0.f};
#pragma unroll
        for (int k = 0; k < 16; ++k) {
            const float e = __expf(logits[k] - m);
            esum += e;
#pragma unroll
            for (int j = 0; j < 4; ++j)
                qq[j] += e * (float)((k >> j) & 1);
        }
        const float qs = scale * __builtin_amdgcn_rcpf(esum);
#pragma unroll
        for (int j = 0; j < 4; ++j) q[t][j] = qq[j] * qs;
    }

    // ---- phase 2: out = x + q.W_from^T; x from regs, W_from from L2 ----
#pragma unroll
    for (int s = 0; s < NSTRIP; ++s) {
        const int fi = s * 64 + lane;
        const int d  = fi * 4;
        const f4 wf0 = WF4[d + 0];
        const f4 wf1 = WF4[d + 1];
        const f4 wf2 = WF4[d + 2];
        const f4 wf3 = WF4[d + 3];
        f4 o0, o1;
        o0.x = xa[s].x + q[0][0]*wf0.x + q[0][1]*wf0.y + q[0][2]*wf0.z + q[0][3]*wf0.w;
        o0.y = xa[s].y + q[0][0]*wf1.x + q[0][1]*wf1.y + q[0][2]*wf1.z + q[0][3]*wf1.w;
        o0.z = xa[s].z + q[0][0]*wf2.x + q[0][1]*wf2.y + q[0][2]*wf2.z + q[0][3]*wf2.w;
        o0.w = xa[s].w + q[0][0]*wf3.x + q[0][1]*wf3.y + q[0][2]*wf3.z + q[0][3]*wf3.w;
        o1.x = xbv[s].x + q[1][0]*wf0.x + q[1][1]*wf0.y + q[1][2]*wf0.z + q[1][3]*wf0.w;
        o1.y = xbv[s].y + q[1][0]*wf1.x + q[1][1]*wf1.y + q[1][2]*wf1.z + q[1][3]*wf1.w;
        o1.z = xbv[s].z + q[1][0]*wf2.x + q[1][1]*wf2.y + q[1][2]*wf2.z + q[1][3]*wf2.w;
        o1.w = xbv[s].w + q[1][0]*wf3.x + q[1][1]*wf3.y + q[1][2]*wf3.z + q[1][3]*wf3.w;
        __builtin_nontemporal_store(o0, &O4[xb0 + fi]);
        __builtin_nontemporal_store(o1, &O4[xb1 + fi]);
    }
}

extern "C" void kernel_launch(void* const* d_in, const int* in_sizes, int n_in,
                              void* d_out, int out_size, void* d_ws, size_t ws_size,
                              hipStream_t stream) {
    const float* x        = (const float*)d_in[0];
    const float* W_to     = (const float*)d_in[1];
    const float* W_from   = (const float*)d_in[2];
    const float* log_temp = (const float*)d_in[3];
    const float* scale    = (const float*)d_in[4];
    float* out = (float*)d_out;

    const int n_tokens = in_sizes[0] / D_MODEL;     // 16384
    const int tok_per_block = 4 * 2;                // 4 waves x 2 tokens
    const int blocks = (n_tokens + tok_per_block - 1) / tok_per_block;
    hypercube_fused_kernel<<<blocks, THREADS, 0, stream>>>(
        x, W_to, W_from, log_temp, scale, out, n_tokens);
}

// Round 7
// 62.968 us; speedup vs baseline: 1.4583x; 1.4583x over previous
//
#include <hip/hip_runtime.h>

#define D_MODEL   2048
#define F4T       (D_MODEL / 4)        // 512 float4 per token
#define THREADS   256
#define NSTRIP    8                    // D_MODEL / (64 lanes * 4 floats)

typedef float f4 __attribute__((ext_vector_type(4)));

// Fused: one wave per token. x read from HBM exactly once (held in VGPRs),
// W_to/W_from served from L1/L2, out written nontemporally (keeps x L3-hot).
// Fast hw transcendentals (validated in R6: absmax unchanged at 0.0156).
__global__ __launch_bounds__(THREADS, 4)
void hypercube_fused_kernel(const float* __restrict__ x,
                            const float* __restrict__ W_to,
                            const float* __restrict__ W_from,
                            const float* __restrict__ log_temp,
                            const float* __restrict__ scale_p,
                            float* __restrict__ out,
                            int n_tokens)
{
    const int tid   = threadIdx.x;
    const int lane  = tid & 63;
    const int wave  = tid >> 6;
    const int token = blockIdx.x * 4 + wave;
    if (token >= n_tokens) return;

    const f4* __restrict__ X4  = reinterpret_cast<const f4*>(x);
    const f4* __restrict__ WT4 = reinterpret_cast<const f4*>(W_to);
    const f4* __restrict__ WF4 = reinterpret_cast<const f4*>(W_from);
    f4* __restrict__ O4 = reinterpret_cast<f4*>(out);

    const size_t xb = (size_t)token * F4T;

    // ---- issue ALL x loads first (8 independent dwordx4 / lane) ----
    f4 xr[NSTRIP];
#pragma unroll
    for (int s = 0; s < NSTRIP; ++s)
        xr[s] = X4[xb + s * 64 + lane];

    // ---- projection: z[k] = sum_d x[d]*W_to[k][d]; W_to from L1/L2 ----
    float z[4] = {0.f, 0.f, 0.f, 0.f};
#pragma unroll
    for (int s = 0; s < NSTRIP; ++s) {
        const int fi = s * 64 + lane;
        const f4 w0 = WT4[0*512 + fi];
        const f4 w1 = WT4[1*512 + fi];
        const f4 w2 = WT4[2*512 + fi];
        const f4 w3 = WT4[3*512 + fi];
        const f4 a  = xr[s];
        z[0] += a.x*w0.x + a.y*w0.y + a.z*w0.z + a.w*w0.w;
        z[1] += a.x*w1.x + a.y*w1.y + a.z*w1.z + a.w*w1.w;
        z[2] += a.x*w2.x + a.y*w2.y + a.z*w2.z + a.w*w2.w;
        z[3] += a.x*w3.x + a.y*w3.y + a.z*w3.z + a.w*w3.w;
    }

    // ---- wave64 butterfly reduce (4 sums) — no LDS, no barrier ----
#pragma unroll
    for (int off = 32; off >= 1; off >>= 1) {
#pragma unroll
        for (int k = 0; k < 4; ++k)
            z[k] += __shfl_xor(z[k], off);
    }

    // ---- scalars ----
    float temp = __expf(log_temp[0]);
    temp = fminf(fmaxf(temp, 0.01f), 5.0f);
    const float inv_temp = 1.0f / temp;
    const float scale = scale_p[0];

    // ---- softmax over 16 hypercube vertices (hw v_exp/v_sqrt/v_rcp) ----
    float logits[16];
    float m = -1e30f;
#pragma unroll
    for (int k = 0; k < 16; ++k) {
        float ssum = 0.f;
#pragma unroll
        for (int j = 0; j < 4; ++j) {
            const float dz = z[j] - (float)((k >> j) & 1);
            ssum += dz * dz;
        }
        logits[k] = -__builtin_amdgcn_sqrtf(ssum) * inv_temp;
        m = fmaxf(m, logits[k]);
    }
    float esum = 0.f;
    float qq[4] = {0.f, 0.f, 0.f, 0.f};
#pragma unroll
    for (int k = 0; k < 16; ++k) {
        const float e = __expf(logits[k] - m);
        esum += e;
#pragma unroll
        for (int j = 0; j < 4; ++j)
            qq[j] += e * (float)((k >> j) & 1);
    }
    const float qs = scale * __builtin_amdgcn_rcpf(esum);
    const float q0 = qq[0]*qs, q1 = qq[1]*qs, q2 = qq[2]*qs, q3 = qq[3]*qs;

    // ---- phase 2: out = x + q . W_from^T; x from regs, W_from from L1/L2 --
#pragma unroll
    for (int s = 0; s < NSTRIP; ++s) {
        const int fi = s * 64 + lane;
        const int d  = fi * 4;
        const f4 wf0 = WF4[d + 0];
        const f4 wf1 = WF4[d + 1];
        const f4 wf2 = WF4[d + 2];
        const f4 wf3 = WF4[d + 3];
        f4 o;
        o.x = xr[s].x + q0*wf0.x + q1*wf0.y + q2*wf0.z + q3*wf0.w;
        o.y = xr[s].y + q0*wf1.x + q1*wf1.y + q2*wf1.z + q3*wf1.w;
        o.z = xr[s].z + q0*wf2.x + q1*wf2.y + q2*wf2.z + q3*wf2.w;
        o.w = xr[s].w + q0*wf3.x + q1*wf3.y + q2*wf3.z + q3*wf3.w;
        __builtin_nontemporal_store(o, &O4[xb + fi]);
    }
}

extern "C" void kernel_launch(void* const* d_in, const int* in_sizes, int n_in,
                              void* d_out, int out_size, void* d_ws, size_t ws_size,
                              hipStream_t stream) {
    const float* x        = (const float*)d_in[0];
    const float* W_to     = (const float*)d_in[1];
    const float* W_from   = (const float*)d_in[2];
    const float* log_temp = (const float*)d_in[3];
    const float* scale    = (const float*)d_in[4];
    float* out = (float*)d_out;

    const int n_tokens = in_sizes[0] / D_MODEL;       // 16384
    const int blocks = (n_tokens + 3) / 4;            // 4 waves/block, 1 token/wave
    hypercube_fused_kernel<<<blocks, THREADS, 0, stream>>>(
        x, W_to, W_from, log_temp, scale, out, n_tokens);
}

// Round 8
// 50.170 us; speedup vs baseline: 1.8303x; 1.2551x over previous
//
#include <hip/hip_runtime.h>

#define D_MODEL   2048
#define F4T       (D_MODEL / 4)        // 512 float4 per token
#define THREADS   512                  // 8 waves
#define NSTRIP    8                    // D_MODEL / (64 lanes * 4 floats)
#define TOK_PER_WAVE 2
#define TOK_PER_ITER (8 * TOK_PER_WAVE)   // 16
#define ITERS     2
#define TOK_PER_BLOCK (TOK_PER_ITER * ITERS)  // 32

typedef float f4 __attribute__((ext_vector_type(4)));

// Fused, LDS-staged weights. W_to kept [k][d]; W_from stored TRANSPOSED [k][d]
// so phase-2 LDS reads are unit-stride ds_read_b128 (conflict-free).
// Each block: stage W once (64 KB LDS), then 8 waves x 2 tokens x 2 iters.
__global__ __launch_bounds__(THREADS)
void hypercube_fused_kernel(const float* __restrict__ x,
                            const float* __restrict__ W_to,
                            const float* __restrict__ W_from,
                            const float* __restrict__ log_temp,
                            const float* __restrict__ scale_p,
                            float* __restrict__ out,
                            int n_tokens)
{
    __shared__ f4    sWT[4 * F4T];        // W_to  [k][d] as f4: 32 KB
    __shared__ float sWFT[4 * D_MODEL];   // W_from^T [k][d]:     32 KB

    const int tid  = threadIdx.x;
    const int lane = tid & 63;
    const int wave = tid >> 6;

    const f4* __restrict__ X4  = reinterpret_cast<const f4*>(x);
    const f4* __restrict__ WT4 = reinterpret_cast<const f4*>(W_to);
    const f4* __restrict__ WF4 = reinterpret_cast<const f4*>(W_from);
    f4* __restrict__ O4 = reinterpret_cast<f4*>(out);

    // ---- stage W_to (straight copy) and W_from (transpose) into LDS ----
#pragma unroll
    for (int j = 0; j < 4; ++j)
        sWT[tid + j * THREADS] = WT4[tid + j * THREADS];
#pragma unroll
    for (int j = 0; j < 4; ++j) {
        const int d = tid + j * THREADS;          // row of W_from
        const f4 w = WF4[d];                      // [k0..k3]
        sWFT[0 * D_MODEL + d] = w.x;              // bank = d%32: conflict-free
        sWFT[1 * D_MODEL + d] = w.y;
        sWFT[2 * D_MODEL + d] = w.z;
        sWFT[3 * D_MODEL + d] = w.w;
    }
    __syncthreads();

    const f4* __restrict__ sWFT4 = reinterpret_cast<const f4*>(sWFT);

    // ---- scalars (L2-resident broadcast loads) ----
    float temp = __expf(log_temp[0]);
    temp = fminf(fmaxf(temp, 0.01f), 5.0f);
    const float inv_temp = 1.0f / temp;
    const float scale = scale_p[0];

    const int blockBase = blockIdx.x * TOK_PER_BLOCK;

#pragma unroll 1
    for (int it = 0; it < ITERS; ++it) {
        const int tok0 = blockBase + it * TOK_PER_ITER + wave * TOK_PER_WAVE;
        if (tok0 >= n_tokens) break;
        const size_t xb0 = (size_t)tok0 * F4T;
        const size_t xb1 = xb0 + F4T;

        // ---- front-load ALL x loads (16 independent dwordx4) ----
        f4 xa[NSTRIP], xc[NSTRIP];
#pragma unroll
        for (int s = 0; s < NSTRIP; ++s)
            xa[s] = X4[xb0 + s * 64 + lane];
#pragma unroll
        for (int s = 0; s < NSTRIP; ++s)
            xc[s] = X4[xb1 + s * 64 + lane];

        // ---- phase 1: z[t][k] = sum_d x*W_to[k], W_to from LDS ----
        float z0[4] = {0.f,0.f,0.f,0.f};
        float z1[4] = {0.f,0.f,0.f,0.f};
#pragma unroll
        for (int s = 0; s < NSTRIP; ++s) {
            const int fi = s * 64 + lane;
            const f4 w0 = sWT[0*512 + fi];
            const f4 w1 = sWT[1*512 + fi];
            const f4 w2 = sWT[2*512 + fi];
            const f4 w3 = sWT[3*512 + fi];
            const f4 a = xa[s];
            const f4 b = xc[s];
            z0[0] += a.x*w0.x + a.y*w0.y + a.z*w0.z + a.w*w0.w;
            z0[1] += a.x*w1.x + a.y*w1.y + a.z*w1.z + a.w*w1.w;
            z0[2] += a.x*w2.x + a.y*w2.y + a.z*w2.z + a.w*w2.w;
            z0[3] += a.x*w3.x + a.y*w3.y + a.z*w3.z + a.w*w3.w;
            z1[0] += b.x*w0.x + b.y*w0.y + b.z*w0.z + b.w*w0.w;
            z1[1] += b.x*w1.x + b.y*w1.y + b.z*w1.z + b.w*w1.w;
            z1[2] += b.x*w2.x + b.y*w2.y + b.z*w2.z + b.w*w2.w;
            z1[3] += b.x*w3.x + b.y*w3.y + b.z*w3.z + b.w*w3.w;
        }

        // ---- wave64 butterfly reduce (8 sums) ----
#pragma unroll
        for (int off = 32; off >= 1; off >>= 1) {
#pragma unroll
            for (int k = 0; k < 4; ++k) {
                z0[k] += __shfl_xor(z0[k], off);
                z1[k] += __shfl_xor(z1[k], off);
            }
        }

        // ---- softmax over 16 vertices (hw transcendentals) ----
        float q[2][4];
#pragma unroll
        for (int t = 0; t < 2; ++t) {
            const float* zz = (t == 0) ? z0 : z1;
            float logits[16];
            float m = -1e30f;
#pragma unroll
            for (int k = 0; k < 16; ++k) {
                float ssum = 0.f;
#pragma unroll
                for (int j = 0; j < 4; ++j) {
                    const float dz = zz[j] - (float)((k >> j) & 1);
                    ssum += dz * dz;
                }
                logits[k] = -__builtin_amdgcn_sqrtf(ssum) * inv_temp;
                m = fmaxf(m, logits[k]);
            }
            float esum = 0.f;
            float qq[4] = {0.f,0.f,0.f,0.f};
#pragma unroll
            for (int k = 0; k < 16; ++k) {
                const float e = __expf(logits[k] - m);
                esum += e;
#pragma unroll
                for (int j = 0; j < 4; ++j)
                    qq[j] += e * (float)((k >> j) & 1);
            }
            const float qs = scale * __builtin_amdgcn_rcpf(esum);
#pragma unroll
            for (int j = 0; j < 4; ++j) q[t][j] = qq[j] * qs;
        }

        // ---- phase 2: out = x + sum_k q[k]*WFT[k][d], WFT from LDS ----
#pragma unroll
        for (int s = 0; s < NSTRIP; ++s) {
            const int fi = s * 64 + lane;
            const f4 wk0 = sWFT4[0*512 + fi];
            const f4 wk1 = sWFT4[1*512 + fi];
            const f4 wk2 = sWFT4[2*512 + fi];
            const f4 wk3 = sWFT4[3*512 + fi];
            f4 o0 = xa[s] + q[0][0]*wk0 + q[0][1]*wk1 + q[0][2]*wk2 + q[0][3]*wk3;
            f4 o1 = xc[s] + q[1][0]*wk0 + q[1][1]*wk1 + q[1][2]*wk2 + q[1][3]*wk3;
            __builtin_nontemporal_store(o0, &O4[xb0 + fi]);
            __builtin_nontemporal_store(o1, &O4[xb1 + fi]);
        }
    }
}

extern "C" void kernel_launch(void* const* d_in, const int* in_sizes, int n_in,
                              void* d_out, int out_size, void* d_ws, size_t ws_size,
                              hipStream_t stream) {
    const float* x        = (const float*)d_in[0];
    const float* W_to     = (const float*)d_in[1];
    const float* W_from   = (const float*)d_in[2];
    const float* log_temp = (const float*)d_in[3];
    const float* scale    = (const float*)d_in[4];
    float* out = (float*)d_out;

    const int n_tokens = in_sizes[0] / D_MODEL;      // 16384
    const int blocks = (n_tokens + TOK_PER_BLOCK - 1) / TOK_PER_BLOCK;  // 512
    hypercube_fused_kernel<<<blocks, THREADS, 0, stream>>>(
        x, W_to, W_from, log_temp, scale, out, n_tokens);
}